// Round 2
// baseline (140.699 us; speedup 1.0000x reference)
//
#include <hip/hip_runtime.h>
#include <hip/hip_bf16.h>
#include <stdint.h>

// TripletLoss (n=4096, d=2048, K=4) — fused bf16-MFMA distance + mining.
//   1. prep: fp32 -> bf16 matrix (ws) + row sum-of-squares sq[] + neg_min init
//   2. gemm: upper-tri 128x128 tiles of A@A^T, 2-phase double-buffered LDS,
//      balanced 1D triangular grid (528 blocks) + bijective XCD swizzle.
//      Fused epilogue: dist = sqrt(max(sq_i+sq_j-2*dot,1e-12)); row+col mins
//      -> atomicMin; diagonal tiles emit within-identity dist_ap.
//   3. finalize: loss = mean(relu(ap - an + margin)), prec = mean(an > ap)

#define N_ROWS 4096
#define DIM    2048
#define P_IDS  1024
#define NPAIR  (P_IDS * 6)
#define MARGIN 0.3f
#define BK     64
#define NT     (DIM / BK)   // 32 K-steps
#define NTILE  32           // 4096 / 128
#define NBLK   528          // NTILE*(NTILE+1)/2

typedef unsigned short u16;
typedef __attribute__((ext_vector_type(8))) short bf16x8;
typedef __attribute__((ext_vector_type(4))) float f32x4;

__device__ __forceinline__ u16 f2bf(float f) {
    unsigned u = __float_as_uint(f);
    unsigned r = (u + 0x7fffu + ((u >> 16) & 1u)) >> 16;  // RTNE
    return (u16)r;
}

__global__ __launch_bounds__(256) void prep_kernel(const float* __restrict__ in,
                                                   u16* __restrict__ bfm,
                                                   float* __restrict__ sq,
                                                   unsigned* __restrict__ neg_bits) {
    const int row = blockIdx.x;
    const int t = threadIdx.x;
    const float4* rp = (const float4*)(in + (size_t)row * DIM);
    float4 v0 = rp[t * 2 + 0];
    float4 v1 = rp[t * 2 + 1];
    float s = v0.x * v0.x + v0.y * v0.y + v0.z * v0.z + v0.w * v0.w
            + v1.x * v1.x + v1.y * v1.y + v1.z * v1.z + v1.w * v1.w;
    uint4 o;
    o.x = (unsigned)f2bf(v0.x) | ((unsigned)f2bf(v0.y) << 16);
    o.y = (unsigned)f2bf(v0.z) | ((unsigned)f2bf(v0.w) << 16);
    o.z = (unsigned)f2bf(v1.x) | ((unsigned)f2bf(v1.y) << 16);
    o.w = (unsigned)f2bf(v1.z) | ((unsigned)f2bf(v1.w) << 16);
    ((uint4*)(bfm + (size_t)row * DIM))[t] = o;
    #pragma unroll
    for (int m = 32; m; m >>= 1) s += __shfl_down(s, m, 64);
    __shared__ float red[4];
    if ((t & 63) == 0) red[t >> 6] = s;
    __syncthreads();
    if (t == 0) {
        sq[row] = red[0] + red[1] + red[2] + red[3];
        neg_bits[row] = 0x7F800000u;  // +inf
    }
}

__global__ __launch_bounds__(256) void gemm_kernel(const u16* __restrict__ bfm,
                                                   const float* __restrict__ sq,
                                                   unsigned* __restrict__ neg_bits,
                                                   float* __restrict__ dist_ap) {
    // Bijective XCD-chunk swizzle (528 = 8 * 66): each XCD gets 66 consecutive
    // triangular tiles -> A-panel reuse inside one XCD's L2.
    const int bid = (blockIdx.x & 7) * (NBLK / 8) + (blockIdx.x >> 3);
    // Triangular decode: bid -> (bi, bj), bi <= bj, row-major in upper tri.
    int rem = bid, bi = 0;
    while (rem >= NTILE - bi) { rem -= NTILE - bi; ++bi; }
    const int bj = bi + rem;

    __shared__ u16 As[2][128][BK];
    __shared__ u16 Bs[2][128][BK];
    const int t = threadIdx.x;
    const int lane = t & 63;
    const int wave = t >> 6;
    const int wr = (wave >> 1) * 64;   // wave row offset in tile
    const int wc = (wave & 1) * 64;    // wave col offset in tile
    const int lr = lane & 15;          // fragment row/col selector
    const int lk = (lane >> 4) * 8;    // k-offset within 32
    f32x4 acc[4][4] = {};

    const int rowA0 = bi * 128;
    const int rowB0 = bj * 128;
    const int srcRow = lane >> 3;        // 0..7 within 8-row chunk
    const int srcCol = (lane & 7) * 8;   // bf16 col offset (16B granules)
    const int chunkRow = (wave * 4) * 8 + srcRow;  // first of this wave's 4 chunks
    const u16* gA0 = bfm + (size_t)(rowA0 + chunkRow) * DIM + srcCol;
    const u16* gB0 = bfm + (size_t)(rowB0 + chunkRow) * DIM + srcCol;

    // STAGE(buf, kstep): each wave fills 4 consecutive 8-row chunks per matrix.
    #define STAGE(BUF, KK)                                                        \
        do {                                                                      \
            _Pragma("unroll")                                                     \
            for (int is = 0; is < 4; ++is) {                                      \
                const int chunk = wave * 4 + is;                                  \
                __builtin_amdgcn_global_load_lds(                                 \
                    (const __attribute__((address_space(1))) void*)(gA0 + (size_t)is * 8 * DIM + (KK)), \
                    (__attribute__((address_space(3))) void*)((char*)&As[BUF][0][0] + chunk * 1024),    \
                    16, 0, 0);                                                    \
                __builtin_amdgcn_global_load_lds(                                 \
                    (const __attribute__((address_space(1))) void*)(gB0 + (size_t)is * 8 * DIM + (KK)), \
                    (__attribute__((address_space(3))) void*)((char*)&Bs[BUF][0][0] + chunk * 1024),    \
                    16, 0, 0);                                                    \
            }                                                                     \
        } while (0)

    STAGE(0, 0);
    __syncthreads();  // drains vmcnt(0): buf0 ready

    for (int ti = 0; ti < NT; ++ti) {
        const int cur = ti & 1;
        if (ti + 1 < NT) STAGE(cur ^ 1, (ti + 1) * BK);  // prefetch in flight over MFMA
        #pragma unroll
        for (int ks = 0; ks < BK / 32; ++ks) {
            bf16x8 af[4], bfr[4];
            #pragma unroll
            for (int m = 0; m < 4; ++m)
                af[m] = *(const bf16x8*)&As[cur][wr + m * 16 + lr][ks * 32 + lk];
            #pragma unroll
            for (int n = 0; n < 4; ++n)
                bfr[n] = *(const bf16x8*)&Bs[cur][wc + n * 16 + lr][ks * 32 + lk];
            #pragma unroll
            for (int m = 0; m < 4; ++m)
                #pragma unroll
                for (int n = 0; n < 4; ++n)
                    acc[m][n] = __builtin_amdgcn_mfma_f32_16x16x32_bf16(
                        af[m], bfr[n], acc[m][n], 0, 0, 0);
        }
        __syncthreads();  // one vmcnt-drain + barrier per K-step
    }
    #undef STAGE

    // ---- fused epilogue ----
    const bool diag = (bi == bj);
    const int crow_base = rowA0 + wr + (lane >> 4) * 4;  // + m*16 + r
    const int ccol_base = rowB0 + wc + (lane & 15);      // + n*16
    float rowmin[4][4];
    float colmin[4];
    #pragma unroll
    for (int m = 0; m < 4; ++m)
        #pragma unroll
        for (int r = 0; r < 4; ++r) rowmin[m][r] = INFINITY;
    #pragma unroll
    for (int n = 0; n < 4; ++n) colmin[n] = INFINITY;

    #pragma unroll
    for (int m = 0; m < 4; ++m) {
        #pragma unroll
        for (int n = 0; n < 4; ++n) {
            const int gcol = ccol_base + n * 16;
            const float sqc = sq[gcol];
            #pragma unroll
            for (int r = 0; r < 4; ++r) {
                const int grow = crow_base + m * 16 + r;
                const float d2 = sq[grow] + sqc - 2.0f * acc[m][n][r];
                const float d = sqrtf(fmaxf(d2, 1e-12f));
                float cand = d;
                if (diag && ((grow >> 2) == (gcol >> 2))) {
                    if (grow < gcol) {  // within-identity pair (a<b)
                        const int p = grow >> 2;
                        const int a = grow & 3, b = gcol & 3;
                        const int idx = (a * (7 - a)) / 2 + (b - a - 1);
                        dist_ap[p * 6 + idx] = d;
                    }
                    cand = INFINITY;  // mask positives from negative mining
                }
                rowmin[m][r] = fminf(rowmin[m][r], cand);
                colmin[n] = fminf(colmin[n], cand);
            }
        }
    }
    // row-min: reduce across the 16 lanes sharing (lane>>4) (they span cols)
    #pragma unroll
    for (int m = 0; m < 4; ++m)
        #pragma unroll
        for (int r = 0; r < 4; ++r) {
            float v = rowmin[m][r];
            v = fminf(v, __shfl_xor(v, 1, 64));
            v = fminf(v, __shfl_xor(v, 2, 64));
            v = fminf(v, __shfl_xor(v, 4, 64));
            v = fminf(v, __shfl_xor(v, 8, 64));
            if ((lane & 15) == 0) {
                const int grow = crow_base + m * 16 + r;
                atomicMin(&neg_bits[grow], __float_as_uint(v));
            }
        }
    // col-min (transpose contribution): reduce across lane>>4 groups
    if (!diag) {
        #pragma unroll
        for (int n = 0; n < 4; ++n) {
            float v = colmin[n];
            v = fminf(v, __shfl_xor(v, 16, 64));
            v = fminf(v, __shfl_xor(v, 32, 64));
            if ((lane >> 4) == 0) {
                atomicMin(&neg_bits[ccol_base + n * 16], __float_as_uint(v));
            }
        }
    }
}

__global__ __launch_bounds__(256) void finalize_kernel(const unsigned* __restrict__ neg_bits,
                                                       const float* __restrict__ dist_ap,
                                                       float* __restrict__ out) {
    const int t = threadIdx.x;
    float sum = 0.f, cnt = 0.f;
    for (int e = t; e < NPAIR; e += 256) {
        const int p = e / 6;
        const int idx = e - p * 6;
        const int a = (idx < 3) ? 0 : ((idx < 5) ? 1 : 2);  // triu jj for K=4
        const float an = __uint_as_float(neg_bits[p * 4 + a]);
        const float ap = dist_ap[e];
        sum += fmaxf(ap - an + MARGIN, 0.f);
        cnt += (an > ap) ? 1.f : 0.f;
    }
    #pragma unroll
    for (int m = 32; m; m >>= 1) {
        sum += __shfl_down(sum, m, 64);
        cnt += __shfl_down(cnt, m, 64);
    }
    __shared__ float rs[4], rc[4];
    if ((t & 63) == 0) { rs[t >> 6] = sum; rc[t >> 6] = cnt; }
    __syncthreads();
    if (t == 0) {
        out[0] = (rs[0] + rs[1] + rs[2] + rs[3]) / (float)NPAIR;
        out[1] = (rc[0] + rc[1] + rc[2] + rc[3]) / (float)NPAIR;
    }
}

extern "C" void kernel_launch(void* const* d_in, const int* in_sizes, int n_in,
                              void* d_out, int out_size, void* d_ws, size_t ws_size,
                              hipStream_t stream) {
    const float* inputs = (const float*)d_in[0];
    float* out = (float*)d_out;
    char* ws = (char*)d_ws;
    u16* bfm = (u16*)ws;                                       // 16 MiB
    float* sq = (float*)(ws + (size_t)N_ROWS * DIM * 2);       // 16 KiB
    unsigned* neg_bits = (unsigned*)((char*)sq + N_ROWS * 4);  // 16 KiB
    float* dist_ap = (float*)((char*)neg_bits + N_ROWS * 4);   // 24 KiB

    prep_kernel<<<N_ROWS, 256, 0, stream>>>(inputs, bfm, sq, neg_bits);
    gemm_kernel<<<NBLK, 256, 0, stream>>>(bfm, sq, neg_bits, dist_ap);
    finalize_kernel<<<1, 256, 0, stream>>>(neg_bits, dist_ap, out);
}

// Round 3
// 116.047 us; speedup vs baseline: 1.2124x; 1.2124x over previous
//
#include <hip/hip_runtime.h>
#include <hip/hip_bf16.h>
#include <stdint.h>

// TripletLoss (n=4096, d=2048, K=4) — fused bf16-MFMA distance + mining.
//   1. prep: fp32 -> bf16 matrix (ws) + row sum-of-squares sq[] + neg_min init
//   2. gemm: upper-tri 128x128 tiles of A@A^T, 512 threads (8 waves, 2Mx4N),
//      2-phase double-buffered LDS with XOR-swizzled staging (conflict-free
//      ds_read_b128), balanced triangular grid + bijective XCD swizzle.
//      Fused epilogue: dist = sqrt(max(sq_i+sq_j-2*dot,1e-12)); row+col mins
//      -> atomicMin; diagonal tiles emit within-identity dist_ap.
//   3. finalize: loss = mean(relu(ap - an + margin)), prec = mean(an > ap)

#define N_ROWS 4096
#define DIM    2048
#define P_IDS  1024
#define NPAIR  (P_IDS * 6)
#define MARGIN 0.3f
#define BK     64
#define NT     (DIM / BK)   // 32 K-steps
#define NTILE  32           // 4096 / 128
#define NBLK   528          // NTILE*(NTILE+1)/2

typedef unsigned short u16;
typedef __attribute__((ext_vector_type(8))) short bf16x8;
typedef __attribute__((ext_vector_type(4))) float f32x4;

__device__ __forceinline__ u16 f2bf(float f) {
    unsigned u = __float_as_uint(f);
    unsigned r = (u + 0x7fffu + ((u >> 16) & 1u)) >> 16;  // RTNE
    return (u16)r;
}

__global__ __launch_bounds__(256) void prep_kernel(const float* __restrict__ in,
                                                   u16* __restrict__ bfm,
                                                   float* __restrict__ sq,
                                                   unsigned* __restrict__ neg_bits) {
    const int row = blockIdx.x;
    const int t = threadIdx.x;
    const float4* rp = (const float4*)(in + (size_t)row * DIM);
    float4 v0 = rp[t * 2 + 0];
    float4 v1 = rp[t * 2 + 1];
    float s = v0.x * v0.x + v0.y * v0.y + v0.z * v0.z + v0.w * v0.w
            + v1.x * v1.x + v1.y * v1.y + v1.z * v1.z + v1.w * v1.w;
    uint4 o;
    o.x = (unsigned)f2bf(v0.x) | ((unsigned)f2bf(v0.y) << 16);
    o.y = (unsigned)f2bf(v0.z) | ((unsigned)f2bf(v0.w) << 16);
    o.z = (unsigned)f2bf(v1.x) | ((unsigned)f2bf(v1.y) << 16);
    o.w = (unsigned)f2bf(v1.z) | ((unsigned)f2bf(v1.w) << 16);
    ((uint4*)(bfm + (size_t)row * DIM))[t] = o;
    #pragma unroll
    for (int m = 32; m; m >>= 1) s += __shfl_down(s, m, 64);
    __shared__ float red[4];
    if ((t & 63) == 0) red[t >> 6] = s;
    __syncthreads();
    if (t == 0) {
        sq[row] = red[0] + red[1] + red[2] + red[3];
        neg_bits[row] = 0x7F800000u;  // +inf
    }
}

__global__ __launch_bounds__(512) void gemm_kernel(const u16* __restrict__ bfm,
                                                   const float* __restrict__ sq,
                                                   unsigned* __restrict__ neg_bits,
                                                   float* __restrict__ dist_ap) {
    // Bijective XCD-chunk swizzle (528 = 8 * 66).
    const int bid = (blockIdx.x & 7) * (NBLK / 8) + (blockIdx.x >> 3);
    // Triangular decode: bid -> (bi, bj), bi <= bj, row-major in upper tri.
    int rem = bid, bi = 0;
    while (rem >= NTILE - bi) { rem -= NTILE - bi; ++bi; }
    const int bj = bi + rem;

    __shared__ u16 As[2][128][BK];
    __shared__ u16 Bs[2][128][BK];
    const int t = threadIdx.x;
    const int lane = t & 63;
    const int wave = t >> 6;           // 0..7
    const int wr = (wave >> 2) * 64;   // wave row offset in tile (2 M-waves)
    const int wc = (wave & 3) * 32;    // wave col offset in tile (4 N-waves)
    const int lr = lane & 15;          // fragment row/col selector
    const int lk = (lane >> 4) * 8;    // k-offset within 32
    f32x4 acc[4][2] = {};

    const int rowA0 = bi * 128;
    const int rowB0 = bj * 128;
    // XOR-swizzled staging: global source col pre-swizzled so the linear
    // global_load_lds write lands data at byte offset r*128 + ((g^(r&7))*16).
    const int srcRow = lane >> 3;                           // 0..7 in chunk
    const int srcCol = (((lane & 7) ^ (lane >> 3)) * 8);    // swizzled u16 col
    const int chunkRow = (wave * 2) * 8 + srcRow;           // wave's 1st chunk
    const u16* gA0 = bfm + (size_t)(rowA0 + chunkRow) * DIM + srcCol;
    const u16* gB0 = bfm + (size_t)(rowB0 + chunkRow) * DIM + srcCol;

    // STAGE(buf, kk): each wave fills 2 consecutive 8-row chunks per matrix.
    #define STAGE(BUF, KK)                                                        \
        do {                                                                      \
            _Pragma("unroll")                                                     \
            for (int is = 0; is < 2; ++is) {                                      \
                const int chunk = wave * 2 + is;                                  \
                __builtin_amdgcn_global_load_lds(                                 \
                    (const __attribute__((address_space(1))) void*)(gA0 + (size_t)is * 8 * DIM + (KK)), \
                    (__attribute__((address_space(3))) void*)((char*)&As[BUF][0][0] + chunk * 1024),    \
                    16, 0, 0);                                                    \
                __builtin_amdgcn_global_load_lds(                                 \
                    (const __attribute__((address_space(1))) void*)(gB0 + (size_t)is * 8 * DIM + (KK)), \
                    (__attribute__((address_space(3))) void*)((char*)&Bs[BUF][0][0] + chunk * 1024),    \
                    16, 0, 0);                                                    \
            }                                                                     \
        } while (0)

    STAGE(0, 0);
    __syncthreads();  // drains vmcnt(0): buf0 ready

    for (int ti = 0; ti < NT; ++ti) {
        const int cur = ti & 1;
        if (ti + 1 < NT) STAGE(cur ^ 1, (ti + 1) * BK);  // prefetch over MFMA
        #pragma unroll
        for (int ks = 0; ks < BK / 32; ++ks) {
            // Swizzled read col (row&7 == lr&7 for every fragment row).
            const int csw = (ks * 32 + lk) ^ ((lr & 7) * 8);
            bf16x8 af[4], bfr[2];
            #pragma unroll
            for (int m = 0; m < 4; ++m)
                af[m] = *(const bf16x8*)&As[cur][wr + m * 16 + lr][csw];
            #pragma unroll
            for (int n = 0; n < 2; ++n)
                bfr[n] = *(const bf16x8*)&Bs[cur][wc + n * 16 + lr][csw];
            #pragma unroll
            for (int m = 0; m < 4; ++m)
                #pragma unroll
                for (int n = 0; n < 2; ++n)
                    acc[m][n] = __builtin_amdgcn_mfma_f32_16x16x32_bf16(
                        af[m], bfr[n], acc[m][n], 0, 0, 0);
        }
        __syncthreads();  // one vmcnt-drain + barrier per K-step
    }
    #undef STAGE

    // ---- fused epilogue ----
    const bool diag = (bi == bj);
    const int crow_base = rowA0 + wr + (lane >> 4) * 4;  // + m*16 + r
    const int ccol_base = rowB0 + wc + (lane & 15);      // + n*16
    float rowmin[4][4];
    float colmin[2];
    #pragma unroll
    for (int m = 0; m < 4; ++m)
        #pragma unroll
        for (int r = 0; r < 4; ++r) rowmin[m][r] = INFINITY;
    #pragma unroll
    for (int n = 0; n < 2; ++n) colmin[n] = INFINITY;

    #pragma unroll
    for (int m = 0; m < 4; ++m) {
        #pragma unroll
        for (int n = 0; n < 2; ++n) {
            const int gcol = ccol_base + n * 16;
            const float sqc = sq[gcol];
            #pragma unroll
            for (int r = 0; r < 4; ++r) {
                const int grow = crow_base + m * 16 + r;
                const float d2 = sq[grow] + sqc - 2.0f * acc[m][n][r];
                const float d = sqrtf(fmaxf(d2, 1e-12f));
                float cand = d;
                if (diag && ((grow >> 2) == (gcol >> 2))) {
                    if (grow < gcol) {  // within-identity pair (a<b)
                        const int p = grow >> 2;
                        const int a = grow & 3, b = gcol & 3;
                        const int idx = (a * (7 - a)) / 2 + (b - a - 1);
                        dist_ap[p * 6 + idx] = d;
                    }
                    cand = INFINITY;  // mask positives from negative mining
                }
                rowmin[m][r] = fminf(rowmin[m][r], cand);
                colmin[n] = fminf(colmin[n], cand);
            }
        }
    }
    // row-min: reduce across the 16 lanes spanning this wave's 32 cols
    #pragma unroll
    for (int m = 0; m < 4; ++m)
        #pragma unroll
        for (int r = 0; r < 4; ++r) {
            float v = rowmin[m][r];
            v = fminf(v, __shfl_xor(v, 1, 64));
            v = fminf(v, __shfl_xor(v, 2, 64));
            v = fminf(v, __shfl_xor(v, 4, 64));
            v = fminf(v, __shfl_xor(v, 8, 64));
            if ((lane & 15) == 0) {
                const int grow = crow_base + m * 16 + r;
                atomicMin(&neg_bits[grow], __float_as_uint(v));
            }
        }
    // col-min (transpose contribution): reduce across lane>>4 groups
    if (!diag) {
        #pragma unroll
        for (int n = 0; n < 2; ++n) {
            float v = colmin[n];
            v = fminf(v, __shfl_xor(v, 16, 64));
            v = fminf(v, __shfl_xor(v, 32, 64));
            if ((lane >> 4) == 0) {
                atomicMin(&neg_bits[ccol_base + n * 16], __float_as_uint(v));
            }
        }
    }
}

__global__ __launch_bounds__(256) void finalize_kernel(const unsigned* __restrict__ neg_bits,
                                                       const float* __restrict__ dist_ap,
                                                       float* __restrict__ out) {
    const int t = threadIdx.x;
    float sum = 0.f, cnt = 0.f;
    for (int e = t; e < NPAIR; e += 256) {
        const int p = e / 6;
        const int idx = e - p * 6;
        const int a = (idx < 3) ? 0 : ((idx < 5) ? 1 : 2);  // triu jj for K=4
        const float an = __uint_as_float(neg_bits[p * 4 + a]);
        const float ap = dist_ap[e];
        sum += fmaxf(ap - an + MARGIN, 0.f);
        cnt += (an > ap) ? 1.f : 0.f;
    }
    #pragma unroll
    for (int m = 32; m; m >>= 1) {
        sum += __shfl_down(sum, m, 64);
        cnt += __shfl_down(cnt, m, 64);
    }
    __shared__ float rs[4], rc[4];
    if ((t & 63) == 0) { rs[t >> 6] = sum; rc[t >> 6] = cnt; }
    __syncthreads();
    if (t == 0) {
        out[0] = (rs[0] + rs[1] + rs[2] + rs[3]) / (float)NPAIR;
        out[1] = (rc[0] + rc[1] + rc[2] + rc[3]) / (float)NPAIR;
    }
}

extern "C" void kernel_launch(void* const* d_in, const int* in_sizes, int n_in,
                              void* d_out, int out_size, void* d_ws, size_t ws_size,
                              hipStream_t stream) {
    const float* inputs = (const float*)d_in[0];
    float* out = (float*)d_out;
    char* ws = (char*)d_ws;
    u16* bfm = (u16*)ws;                                       // 16 MiB
    float* sq = (float*)(ws + (size_t)N_ROWS * DIM * 2);       // 16 KiB
    unsigned* neg_bits = (unsigned*)((char*)sq + N_ROWS * 4);  // 16 KiB
    float* dist_ap = (float*)((char*)neg_bits + N_ROWS * 4);   // 24 KiB

    prep_kernel<<<N_ROWS, 256, 0, stream>>>(inputs, bfm, sq, neg_bits);
    gemm_kernel<<<NBLK, 512, 0, stream>>>(bfm, sq, neg_bits, dist_ap);
    finalize_kernel<<<1, 256, 0, stream>>>(neg_bits, dist_ap, out);
}

// Round 4
// 94.055 us; speedup vs baseline: 1.4959x; 1.2338x over previous
//
#include <hip/hip_runtime.h>
#include <hip/hip_bf16.h>
#include <stdint.h>

// TripletLoss (n=4096, d=2048, K=4) — fused bf16-MFMA distance + mining.
//   1. prep: fp32 -> bf16 matrix (ws) + row sum-of-squares sq[] + neg_min init
//   2. gemm: upper-tri 256x256 tiles of A@A^T, m201-style 8-phase schedule:
//      512 thr (2Mx4N waves, 128x64 per wave), BK=64, 128 KiB dbuf LDS,
//      XOR-swizzled staging (conflict-free ds_read_b128), counted vmcnt(4)
//      at phases 4/8 only, s_setprio around MFMA clusters, triangular grid
//      (136 blocks = 8 XCD x 17). Fused epilogue: dist = sqrt(max(
//      sq_i+sq_j-2*dot,1e-12)); row+col mins -> atomicMin; diagonal tiles
//      emit within-identity dist_ap.
//   3. finalize: loss = mean(relu(ap - an + margin)), prec = mean(an > ap)

#define N_ROWS 4096
#define DIM    2048
#define P_IDS  1024
#define NPAIR  (P_IDS * 6)
#define MARGIN 0.3f
#define BK     64
#define NT     (DIM / BK)   // 32 K-tiles
#define NIT    (NT / 2)     // 16 iterations (2 K-tiles each)
#define NTILE2 16           // 4096 / 256
#define NBLK2  136          // NTILE2*(NTILE2+1)/2 = 8*17

typedef unsigned short u16;
typedef __attribute__((ext_vector_type(8))) short bf16x8;
typedef __attribute__((ext_vector_type(4))) float f32x4;

__device__ __forceinline__ u16 f2bf(float f) {
    unsigned u = __float_as_uint(f);
    unsigned r = (u + 0x7fffu + ((u >> 16) & 1u)) >> 16;  // RTNE
    return (u16)r;
}

__global__ __launch_bounds__(256) void prep_kernel(const float* __restrict__ in,
                                                   u16* __restrict__ bfm,
                                                   float* __restrict__ sq,
                                                   unsigned* __restrict__ neg_bits) {
    const int row = blockIdx.x;
    const int t = threadIdx.x;
    const float4* rp = (const float4*)(in + (size_t)row * DIM);
    float4 v0 = rp[t * 2 + 0];
    float4 v1 = rp[t * 2 + 1];
    float s = v0.x * v0.x + v0.y * v0.y + v0.z * v0.z + v0.w * v0.w
            + v1.x * v1.x + v1.y * v1.y + v1.z * v1.z + v1.w * v1.w;
    uint4 o;
    o.x = (unsigned)f2bf(v0.x) | ((unsigned)f2bf(v0.y) << 16);
    o.y = (unsigned)f2bf(v0.z) | ((unsigned)f2bf(v0.w) << 16);
    o.z = (unsigned)f2bf(v1.x) | ((unsigned)f2bf(v1.y) << 16);
    o.w = (unsigned)f2bf(v1.z) | ((unsigned)f2bf(v1.w) << 16);
    ((uint4*)(bfm + (size_t)row * DIM))[t] = o;
    #pragma unroll
    for (int m = 32; m; m >>= 1) s += __shfl_down(s, m, 64);
    __shared__ float red[4];
    if ((t & 63) == 0) red[t >> 6] = s;
    __syncthreads();
    if (t == 0) {
        sq[row] = red[0] + red[1] + red[2] + red[3];
        neg_bits[row] = 0x7F800000u;  // +inf
    }
}

__global__ __launch_bounds__(512, 2) void gemm_kernel(const u16* __restrict__ bfm,
                                                      const float* __restrict__ sq,
                                                      unsigned* __restrict__ neg_bits,
                                                      float* __restrict__ dist_ap) {
    extern __shared__ char smem[];          // 128 KiB dynamic LDS
    u16* const Asb = (u16*)smem;            // [2][256][64] u16 (64 KiB)
    u16* const Bsb = (u16*)(smem + 65536);  // [2][256][64] u16 (64 KiB)
    #define AS(B,R,C) Asb[((B) << 14) + ((R) << 6) + (C)]
    #define BS(B,R,C) Bsb[((B) << 14) + ((R) << 6) + (C)]

    // Bijective XCD-chunk swizzle (136 = 8 * 17).
    const int bid = (blockIdx.x & 7) * (NBLK2 / 8) + (blockIdx.x >> 3);
    int rem = bid, bi = 0;
    while (rem >= NTILE2 - bi) { rem -= NTILE2 - bi; ++bi; }
    const int bj = bi + rem;   // bi <= bj

    const int t = threadIdx.x;
    const int lane = t & 63;
    const int wave = t >> 6;             // 0..7
    const int wr = (wave >> 2) * 128;    // M-half (2 waves)
    const int wc = (wave & 3) * 64;      // N-quarter (4 waves)
    const int lr = lane & 15;
    const int lk = (lane >> 4) * 8;
    f32x4 acc[8][4] = {};

    const int rowA0 = bi * 256;
    const int rowB0 = bj * 256;
    // XOR-swizzled staging: pre-swizzle global col so linear LDS write lands
    // at byte r*128 + ((g ^ (r&7))*16); read applies the same XOR.
    const int sr  = lane >> 3;
    const int scz = ((lane & 7) ^ sr) * 8;
    const u16* gA = bfm + (size_t)(rowA0 + sr) * DIM + scz;
    const u16* gB = bfm + (size_t)(rowB0 + sr) * DIM + scz;

    // Stage one 128-row half-tile (16 KiB) of A or B: 2 gloads/wave.
    #define STAGE_HT(GBASE, LDSB, BUF, H, KT)                                     \
        { _Pragma("unroll")                                                       \
          for (int g = 0; g < 2; ++g) {                                           \
              const int chunk = (H) * 16 + wave * 2 + g;                          \
              __builtin_amdgcn_global_load_lds(                                   \
                  (const __attribute__((address_space(1))) void*)                 \
                      ((GBASE) + (size_t)chunk * 8 * DIM + (KT) * 64),            \
                  (__attribute__((address_space(3))) void*)                       \
                      ((char*)(LDSB) + (BUF) * 32768 + chunk * 1024),             \
                  16, 0, 0);                                                      \
          } }
    #define STAGE_A(BUF, H, KT) STAGE_HT(gA, Asb, BUF, H, KT)
    #define STAGE_B(BUF, H, KT) STAGE_HT(gB, Bsb, BUF, H, KT)

    bf16x8 af[8], bfr0[4], bfr1[4];
    #define LOAD_AF(BUF, MH)                                                      \
        { _Pragma("unroll") for (int m = 0; m < 4; ++m)                           \
          _Pragma("unroll") for (int ks = 0; ks < 2; ++ks)                        \
              af[m * 2 + ks] = *(const bf16x8*)&AS(BUF,                           \
                  wr + ((MH) * 4 + m) * 16 + lr,                                  \
                  (ks * 32 + lk) ^ ((lr & 7) * 8)); }
    #define LOAD_BF(DST, BUF, NH)                                                 \
        { _Pragma("unroll") for (int n = 0; n < 2; ++n)                           \
          _Pragma("unroll") for (int ks = 0; ks < 2; ++ks)                        \
              DST[n * 2 + ks] = *(const bf16x8*)&BS(BUF,                          \
                  wc + ((NH) * 2 + n) * 16 + lr,                                  \
                  (ks * 32 + lk) ^ ((lr & 7) * 8)); }

    #define MFMA_Q(MH, NH, BF)                                                    \
        { __builtin_amdgcn_s_setprio(1);                                          \
          _Pragma("unroll") for (int m = 0; m < 4; ++m)                           \
          _Pragma("unroll") for (int n = 0; n < 2; ++n)                           \
          _Pragma("unroll") for (int ks = 0; ks < 2; ++ks)                        \
              acc[(MH) * 4 + m][(NH) * 2 + n] =                                   \
                  __builtin_amdgcn_mfma_f32_16x16x32_bf16(                        \
                      af[m * 2 + ks], BF[n * 2 + ks],                             \
                      acc[(MH) * 4 + m][(NH) * 2 + n], 0, 0, 0);                  \
          __builtin_amdgcn_s_setprio(0); }

    #define BARR() __builtin_amdgcn_s_barrier()
    #define VMW(N) asm volatile("s_waitcnt vmcnt(" #N ")" ::: "memory")

    // Prologue: A(0), B(0) -> buf0; B(1) -> buf1. (A(1) staged in iter0 ph1-2.)
    STAGE_A(0, 0, 0); STAGE_A(0, 1, 0);
    STAGE_B(0, 0, 0); STAGE_B(0, 1, 0);
    STAGE_B(1, 0, 1); STAGE_B(1, 1, 1);
    VMW(0);
    BARR();

    for (int i = 0; i < NIT - 1; ++i) {
        const int t2 = 2 * i;
        // ph1: compute t2 (buf0) quadrant (0,0); stage A(t2+1).h0 -> buf1
        LOAD_AF(0, 0); LOAD_BF(bfr0, 0, 0);
        STAGE_A(1, 0, t2 + 1);
        BARR(); MFMA_Q(0, 0, bfr0); BARR();
        // ph2
        LOAD_BF(bfr1, 0, 1);
        STAGE_A(1, 1, t2 + 1);
        BARR(); MFMA_Q(0, 1, bfr1); BARR();
        // ph3
        LOAD_AF(0, 1);
        STAGE_B(0, 0, t2 + 2);
        BARR(); MFMA_Q(1, 1, bfr1); BARR();
        // ph4: counted drain (8 oldest = B(t+1), A(t+1) needed by ph5-8)
        STAGE_B(0, 1, t2 + 2);
        BARR(); MFMA_Q(1, 0, bfr0); VMW(4); BARR();
        // ph5: compute t2+1 (buf1); stage A(t2+2).h0 -> buf0
        LOAD_AF(1, 0); LOAD_BF(bfr0, 1, 0);
        STAGE_A(0, 0, t2 + 2);
        BARR(); MFMA_Q(0, 0, bfr0); BARR();
        // ph6
        LOAD_BF(bfr1, 1, 1);
        STAGE_A(0, 1, t2 + 2);
        BARR(); MFMA_Q(0, 1, bfr1); BARR();
        // ph7
        LOAD_AF(1, 1);
        STAGE_B(1, 0, t2 + 3);
        BARR(); MFMA_Q(1, 1, bfr1); BARR();
        // ph8: counted drain (8 oldest = B(t+2), A(t+2) needed next iter)
        STAGE_B(1, 1, t2 + 3);
        BARR(); MFMA_Q(1, 0, bfr0); VMW(4); BARR();
    }
    // Peeled last iteration (t2 = 30): no stages for tiles 32/33.
    {
        LOAD_AF(0, 0); LOAD_BF(bfr0, 0, 0);
        STAGE_A(1, 0, NT - 1);
        BARR(); MFMA_Q(0, 0, bfr0); BARR();
        LOAD_BF(bfr1, 0, 1);
        STAGE_A(1, 1, NT - 1);
        BARR(); MFMA_Q(0, 1, bfr1); BARR();
        LOAD_AF(0, 1);
        BARR(); MFMA_Q(1, 1, bfr1); BARR();
        BARR(); MFMA_Q(1, 0, bfr0); VMW(0); BARR();
        LOAD_AF(1, 0); LOAD_BF(bfr0, 1, 0);
        BARR(); MFMA_Q(0, 0, bfr0); BARR();
        LOAD_BF(bfr1, 1, 1);
        BARR(); MFMA_Q(0, 1, bfr1); BARR();
        LOAD_AF(1, 1);
        BARR(); MFMA_Q(1, 1, bfr1); BARR();
        MFMA_Q(1, 0, bfr0);
    }

    // ---- fused epilogue ----
    const bool diag = (bi == bj);
    const int l4 = lane >> 4, l15 = lane & 15;
    float sqc[4];
    #pragma unroll
    for (int n = 0; n < 4; ++n) sqc[n] = sq[rowB0 + wc + n * 16 + l15];
    float colmin[4] = {INFINITY, INFINITY, INFINITY, INFINITY};

    #pragma unroll
    for (int m = 0; m < 8; ++m) {
        #pragma unroll
        for (int r = 0; r < 4; ++r) {
            const int grow = rowA0 + wr + m * 16 + l4 * 4 + r;
            const float sqr = sq[grow];
            float rmin = INFINITY;
            #pragma unroll
            for (int n = 0; n < 4; ++n) {
                const int gcol = rowB0 + wc + n * 16 + l15;
                const float d2 = sqr + sqc[n] - 2.0f * acc[m][n][r];
                const float d = sqrtf(fmaxf(d2, 1e-12f));
                float cand = d;
                if (diag && ((grow >> 2) == (gcol >> 2))) {
                    if (grow < gcol) {  // within-identity pair (a<b)
                        const int p = grow >> 2;
                        const int a = grow & 3, b = gcol & 3;
                        dist_ap[p * 6 + (a * (7 - a)) / 2 + (b - a - 1)] = d;
                    }
                    cand = INFINITY;  // mask positives from mining
                }
                rmin = fminf(rmin, cand);
                colmin[n] = fminf(colmin[n], cand);
            }
            rmin = fminf(rmin, __shfl_xor(rmin, 1, 64));
            rmin = fminf(rmin, __shfl_xor(rmin, 2, 64));
            rmin = fminf(rmin, __shfl_xor(rmin, 4, 64));
            rmin = fminf(rmin, __shfl_xor(rmin, 8, 64));
            if (l15 == 0) atomicMin(&neg_bits[grow], __float_as_uint(rmin));
        }
    }
    if (!diag) {  // transpose contribution (col mins)
        #pragma unroll
        for (int n = 0; n < 4; ++n) {
            float v = colmin[n];
            v = fminf(v, __shfl_xor(v, 16, 64));
            v = fminf(v, __shfl_xor(v, 32, 64));
            if (l4 == 0)
                atomicMin(&neg_bits[rowB0 + wc + n * 16 + l15], __float_as_uint(v));
        }
    }
}

__global__ __launch_bounds__(256) void finalize_kernel(const unsigned* __restrict__ neg_bits,
                                                       const float* __restrict__ dist_ap,
                                                       float* __restrict__ out) {
    const int t = threadIdx.x;
    float sum = 0.f, cnt = 0.f;
    for (int e = t; e < NPAIR; e += 256) {
        const int p = e / 6;
        const int idx = e - p * 6;
        const int a = (idx < 3) ? 0 : ((idx < 5) ? 1 : 2);  // triu jj for K=4
        const float an = __uint_as_float(neg_bits[p * 4 + a]);
        const float ap = dist_ap[e];
        sum += fmaxf(ap - an + MARGIN, 0.f);
        cnt += (an > ap) ? 1.f : 0.f;
    }
    #pragma unroll
    for (int m = 32; m; m >>= 1) {
        sum += __shfl_down(sum, m, 64);
        cnt += __shfl_down(cnt, m, 64);
    }
    __shared__ float rs[4], rc[4];
    if ((t & 63) == 0) { rs[t >> 6] = sum; rc[t >> 6] = cnt; }
    __syncthreads();
    if (t == 0) {
        out[0] = (rs[0] + rs[1] + rs[2] + rs[3]) / (float)NPAIR;
        out[1] = (rc[0] + rc[1] + rc[2] + rc[3]) / (float)NPAIR;
    }
}

extern "C" void kernel_launch(void* const* d_in, const int* in_sizes, int n_in,
                              void* d_out, int out_size, void* d_ws, size_t ws_size,
                              hipStream_t stream) {
    const float* inputs = (const float*)d_in[0];
    float* out = (float*)d_out;
    char* ws = (char*)d_ws;
    u16* bfm = (u16*)ws;                                       // 16 MiB
    float* sq = (float*)(ws + (size_t)N_ROWS * DIM * 2);       // 16 KiB
    unsigned* neg_bits = (unsigned*)((char*)sq + N_ROWS * 4);  // 16 KiB
    float* dist_ap = (float*)((char*)neg_bits + N_ROWS * 4);   // 24 KiB

    prep_kernel<<<N_ROWS, 256, 0, stream>>>(inputs, bfm, sq, neg_bits);
    gemm_kernel<<<NBLK2, 512, 131072, stream>>>(bfm, sq, neg_bits, dist_ap);
    finalize_kernel<<<1, 256, 0, stream>>>(neg_bits, dist_ap, out);
}